// Round 18
// baseline (275.672 us; speedup 1.0000x reference)
//
#include <hip/hip_runtime.h>

#define DEV __device__ __forceinline__

typedef unsigned short u16;
typedef unsigned int u32;
typedef __bf16 bf16x8 __attribute__((ext_vector_type(8)));
typedef float f32x4 __attribute__((ext_vector_type(4)));

DEV float elu1(float x) { return x > 0.f ? x + 1.f : __expf(x); }

DEV u16 f2bf(float f) {
    union { float f; unsigned u; } v; v.f = f;
    unsigned r = v.u + 0x7fffu + ((v.u >> 16) & 1u);
    return (u16)(r >> 16);
}

DEV float bf2f(u16 h) {
    union { u32 u; float f; } v; v.u = ((u32)h) << 16; return v.f;
}

// ===========================================================================
// prep1 = conv-weight repack (validated R2)  ||  cast_src (validated R5).
// ===========================================================================
__global__ __launch_bounds__(256) void prep1_kernel(
    const float* __restrict__ Wq,
    const float* __restrict__ Wk1, const float* __restrict__ Wk3,
    const float* __restrict__ Wk5, const float* __restrict__ Wk7,
    const float* __restrict__ Wv1, const float* __restrict__ Wv3,
    const float* __restrict__ Wv5, const float* __restrict__ Wv7,
    u16* __restrict__ wpack,
    const float* __restrict__ x, const float* __restrict__ src,
    u16* __restrict__ xbh, u16* __restrict__ sbh)
{
    __shared__ float lds[32 * 129];
    const int t = threadIdx.x;
    if (blockIdx.x < 1632) {
        int gid = blockIdx.x * 256 + t;
        int frag = gid >> 6, l = gid & 63;
        const float* W; int K, ocbase = 0, rel;
        if (frag < 1152) {
            W = Wq; K = 3; int slot = frag / 288; rel = frag % 288; ocbase = slot * 64;
        } else {
            int f = frag - 1152; int side = f / 2688; f %= 2688;
            if (f < 32)        { W = side ? Wv1 : Wk1; K = 1; rel = f; }
            else if (f < 320)  { W = side ? Wv3 : Wk3; K = 3; rel = f - 32; }
            else if (f < 1120) { W = side ? Wv5 : Wk5; K = 5; rel = f - 320; }
            else               { W = side ? Wv7 : Wk7; K = 7; rel = f - 1120; }
        }
        int og = rel & 3, cc = (rel >> 2) & 7, tap = rel >> 5;
        int dy = tap / K, dx = tap % K;
        int oc = ocbase + og * 16 + (l & 15);
        int c0 = cc * 32 + (l >> 4) * 8;
        u16 pk[8];
#pragma unroll
        for (int j = 0; j < 8; ++j)
            pk[j] = f2bf(W[((size_t)(oc * 256 + c0 + j) * K + dy) * K + dx]);
        *(int4*)&wpack[(size_t)frag * 512 + l * 8] = *(const int4*)pk;
        return;
    }
    const int i = blockIdx.x - 1632;    // 1024 cast_src blocks
    const int inp = i >> 9, rem = i & 511;
    const int b = rem >> 6, cc = (rem >> 3) & 7, pxb = rem & 7;
    const float* in = (inp ? src : x) + ((size_t)b * 256 + cc * 32) * 1024 + pxb * 128;
    u16* outp = (inp ? sbh : xbh) + (size_t)b * 262144 + (size_t)cc * 32768 + pxb * 128 * 32;
#pragma unroll
    for (int u = 0; u < 4; ++u) {
        int unit = t + u * 256;
        int r = unit >> 5, px4 = unit & 31;
        float4 v = *(const float4*)(in + (size_t)r * 1024 + px4 * 4);
        lds[r * 129 + px4 * 4 + 0] = v.x;
        lds[r * 129 + px4 * 4 + 1] = v.y;
        lds[r * 129 + px4 * 4 + 2] = v.z;
        lds[r * 129 + px4 * 4 + 3] = v.w;
    }
    __syncthreads();
#pragma unroll
    for (int u = 0; u < 2; ++u) {
        int unit = t + u * 256;
        int px = unit >> 2, cg = unit & 3;
        u16 pk[8];
#pragma unroll
        for (int j = 0; j < 8; ++j) pk[j] = f2bf(lds[(cg * 8 + j) * 129 + px]);
        *(int4*)&outp[px * 32 + cg * 8] = *(const int4*)pk;
    }
}

// ===========================================================================
// MFMA implicit-GEMM conv body (R9 MFMA math + R16 bf16 epilogue, validated).
// ===========================================================================
template<int K>
DEV void conv_mfma_body(const u16* __restrict__ srcb,
                        const u16* __restrict__ wsec,
                        u16* __restrict__ dst,
                        u16* Bt, int y0, int cch0, int ncc, int t)
{
    constexpr int P = K / 2;
    const int w = t >> 6, l = t & 63;
    const int chi = l >> 4, ln = l & 15;
    const int rowbase = chi * 22 + w * 2 + 3 - P;
    const int colbase = ln + 3 - P;
    f32x4 acc[4][4];
#pragma unroll
    for (int m = 0; m < 4; ++m)
#pragma unroll
        for (int n = 0; n < 4; ++n) acc[m][n] = (f32x4){0.f, 0.f, 0.f, 0.f};

    for (int cc = 0; cc < ncc; ++cc) {
        const int ccg = cch0 + cc;
        __syncthreads();
#pragma unroll
        for (int u = 0; u < 7; ++u) {
            int unit = t + (u << 9);
            if (unit < 2816) {
                int xv = unit & 31, r = unit >> 5;
                int yy = r % 22, ch = r / 22;
                int ygl = y0 - 3 + yy;
                int4 pk;
                if ((unsigned)ygl < 32u)
                    pk = *(const int4*)&srcb[(size_t)ccg * 32768 + (ygl * 32 + xv) * 32 + ch * 8];
                else
                    pk = (int4){0, 0, 0, 0};
                *(int4*)&Bt[((ch * 22 + yy) * 40 + xv + 3) * 8] = pk;
            } else if (unit < 3520) {
                int hu = unit - 2816;
                int hx = hu & 7; int xi = hx < 3 ? hx : hx + 32;
                int r = hu >> 3; int yy = r % 22, ch = r / 22;
                int4 z = {0, 0, 0, 0};
                *(int4*)&Bt[((ch * 22 + yy) * 40 + xi) * 8] = z;
            }
        }
        __syncthreads();
#pragma unroll
        for (int dy = 0; dy < K; ++dy) {
#pragma unroll
            for (int dx = 0; dx < K; ++dx) {
                const int tap = dy * K + dx;
                const u16* wp = wsec + ((size_t)(tap * 8 + ccg) * 4) * 512 + l * 8;
                bf16x8 a0 = *(const bf16x8*)(wp);
                bf16x8 a1 = *(const bf16x8*)(wp + 512);
                bf16x8 a2 = *(const bf16x8*)(wp + 1024);
                bf16x8 a3 = *(const bf16x8*)(wp + 1536);
                bf16x8 bf[4];
#pragma unroll
                for (int n = 0; n < 4; ++n) {
                    int row = rowbase + dy + (n >> 1);
                    int col = colbase + dx + (n & 1) * 16;
                    bf[n] = *(const bf16x8*)&Bt[(row * 40 + col) * 8];
                }
#pragma unroll
                for (int n = 0; n < 4; ++n) {
                    acc[0][n] = __builtin_amdgcn_mfma_f32_16x16x32_bf16(a0, bf[n], acc[0][n], 0, 0, 0);
                    acc[1][n] = __builtin_amdgcn_mfma_f32_16x16x32_bf16(a1, bf[n], acc[1][n], 0, 0, 0);
                    acc[2][n] = __builtin_amdgcn_mfma_f32_16x16x32_bf16(a2, bf[n], acc[2][n], 0, 0, 0);
                    acc[3][n] = __builtin_amdgcn_mfma_f32_16x16x32_bf16(a3, bf[n], acc[3][n], 0, 0, 0);
                }
            }
        }
    }
#pragma unroll
    for (int m = 0; m < 4; ++m)
#pragma unroll
        for (int n = 0; n < 4; ++n) {
            int y = y0 + w * 2 + (n >> 1);
            int px = y * 32 + (n & 1) * 16 + ln;
            int ocb = m * 16 + chi * 4;
            u16 pk[4];
#pragma unroll
            for (int r = 0; r < 4; ++r) pk[r] = f2bf(acc[m][n][r]);
            *(uint2*)&dst[(size_t)px * 64 + ocb] = *(const uint2*)pk;
        }
}

// Job decode (R17 load-balanced, validated): bx = b*76 + job; job = j*2 + m.
__global__ __launch_bounds__(512) void conv_mfma_kernel(
    const u16* __restrict__ xbh, const u16* __restrict__ sbh,
    const u16* __restrict__ wpack,
    u16* __restrict__ kbt, u16* __restrict__ vbt,
    u16* __restrict__ pq, u16* __restrict__ p3,
    u16* __restrict__ p5, u16* __restrict__ p7)
{
    __shared__ u16 Bt[4 * 22 * 40 * 8];
    const int bx = blockIdx.x, t = threadIdx.x;
    const int b = bx / 76, job = bx % 76;
    const int m = job & 1, j = job >> 1;
    if (j < 8) {
        int slot = j >> 1, cp = j & 1;
        conv_mfma_body<3>(xbh + (size_t)b * 262144,
                          wpack + (size_t)(slot * 288) * 512,
                          pq + ((size_t)((slot * 2 + cp) * 8 + b)) * 65536,
                          Bt, m * 16, cp * 4, 4, t);
        return;
    }
    const int s2 = j - 8;
    const int side = s2 / 15, jj = s2 % 15;
    const u16* sp = sbh + (size_t)b * 262144;
    u16* fin = side ? vbt : kbt;
    const size_t wkb = 1152 + (size_t)side * 2688;
    if (jj == 0) {
        conv_mfma_body<1>(sp, wpack + (wkb + 0) * 512,
                          fin + ((size_t)(b * 4 + 0)) * 65536, Bt, m * 16, 0, 8, t);
    } else if (jj < 3) {
        int cp = jj - 1;
        conv_mfma_body<3>(sp, wpack + (wkb + 32) * 512,
                          p3 + ((size_t)((side * 2 + cp) * 8 + b)) * 65536,
                          Bt, m * 16, cp * 4, 4, t);
    } else if (jj < 7) {
        int cp = jj - 3;
        conv_mfma_body<5>(sp, wpack + (wkb + 320) * 512,
                          p5 + ((size_t)((side * 4 + cp) * 8 + b)) * 65536,
                          Bt, m * 16, cp * 2, 2, t);
    } else {
        int cp = jj - 7;
        conv_mfma_body<7>(sp, wpack + (wkb + 1120) * 512,
                          p7 + ((size_t)((side * 8 + cp) * 8 + b)) * 65536,
                          Bt, m * 16, cp, 1, t);
    }
}

// ===========================================================================
// prep2 = bf16-partial reduce (80 images) || FF/Wm repack (validated R17).
// ===========================================================================
__global__ __launch_bounds__(256) void prep2_kernel(
    const u16* __restrict__ pq, const u16* __restrict__ p3,
    const u16* __restrict__ p5, const u16* __restrict__ p7,
    u16* __restrict__ qbt, u16* __restrict__ kbt, u16* __restrict__ vbt,
    const float* __restrict__ W1, const float* __restrict__ W2,
    const float* __restrict__ Wm,
    u16* __restrict__ w1p, u16* __restrict__ w2p, u16* __restrict__ wmp)
{
    const int t = threadIdx.x;
    if (blockIdx.x < 2560) {
        int gid = blockIdx.x * 256 + t;     // 655360 units of 8 bf16
        int u8 = gid & 8191;
        int img = gid >> 13;                // 0..79
        const u16* srcb; u16* outb; int parts;
        if (img < 32) {
            int sub = img >> 3, b_ = img & 7;
            parts = 2;
            srcb = pq + ((size_t)(sub * 2) * 8 + b_) * 65536;
            outb = qbt + ((size_t)(b_ * 4 + sub)) * 65536;
        } else if (img < 48) {
            int i2 = img - 32; int sub = i2 >> 3, b_ = i2 & 7;
            parts = 2;
            srcb = p3 + ((size_t)(sub * 2) * 8 + b_) * 65536;
            outb = (sub ? vbt : kbt) + ((size_t)(b_ * 4 + 1)) * 65536;
        } else if (img < 64) {
            int i2 = img - 48; int sub = i2 >> 3, b_ = i2 & 7;
            parts = 4;
            srcb = p5 + ((size_t)(sub * 4) * 8 + b_) * 65536;
            outb = (sub ? vbt : kbt) + ((size_t)(b_ * 4 + 2)) * 65536;
        } else {
            int i2 = img - 64; int sub = i2 >> 3, b_ = i2 & 7;
            parts = 8;
            srcb = p7 + ((size_t)(sub * 8) * 8 + b_) * 65536;
            outb = (sub ? vbt : kbt) + ((size_t)(b_ * 4 + 3)) * 65536;
        }
        float sacc[8];
#pragma unroll
        for (int e = 0; e < 8; ++e) sacc[e] = 0.f;
        for (int p = 0; p < parts; ++p) {
            int4 u = *(const int4*)&srcb[(size_t)p * 524288 + (size_t)u8 * 8];
            const u16* uu = (const u16*)&u;
#pragma unroll
            for (int e = 0; e < 8; ++e) sacc[e] += bf2f(uu[e]);
        }
        u16 pk[8];
#pragma unroll
        for (int e = 0; e < 8; ++e) pk[e] = f2bf(sacc[e]);
        *(int4*)&outb[(size_t)u8 * 8] = *(const int4*)pk;
        return;
    }
    int gid = (blockIdx.x - 2560) * 256 + t;    // 224 blocks, 896 frags
    int f = gid >> 6, l = gid & 63;
    if (f >= 896) return;
    u16 pk[8];
    if (f < 512) {
        int ks = f >> 5, nf = f & 31;
#pragma unroll
        for (int j = 0; j < 8; ++j)
            pk[j] = f2bf(W1[(size_t)(ks * 32 + (l >> 4) * 8 + j) * 512 + nf * 16 + (l & 15)]);
        *(int4*)&w1p[(size_t)f * 512 + l * 8] = *(const int4*)pk;
    } else if (f < 768) {
        int f2 = f - 512;
        int ks = f2 >> 4, nf = f2 & 15;
#pragma unroll
        for (int j = 0; j < 8; ++j)
            pk[j] = f2bf(W2[(size_t)(ks * 32 + (l >> 4) * 8 + j) * 256 + nf * 16 + (l & 15)]);
        *(int4*)&w2p[(size_t)f2 * 512 + l * 8] = *(const int4*)pk;
    } else {
        int f3 = f - 768;
        int ks = f3 >> 4, nf = f3 & 15;
#pragma unroll
        for (int j = 0; j < 8; ++j)
            pk[j] = f2bf(Wm[(size_t)(ks * 32 + (l >> 4) * 8 + j) * 256 + nf * 16 + (l & 15)]);
        *(int4*)&wmp[(size_t)f3 * 512 + l * 8] = *(const int4*)pk;
    }
}

// ===========================================================================
// prep3 = linear-attention KV/Ksum (validated R16). 128 blocks.
// ===========================================================================
__global__ __launch_bounds__(256) void prep3_kernel(
    const u16* __restrict__ kbt, const u16* __restrict__ vbt,
    float* __restrict__ KVp, float* __restrict__ Ksump)
{
    __shared__ float4 smem4[2112];
    float* Kt = (float*)smem4;              // [64][68]
    float* Vt = (float*)(smem4 + 64 * 17);  // [64][64]
    const int t = threadIdx.x;
    const int bx = blockIdx.x;              // 128
    const int b = bx >> 4, h = (bx >> 2) & 3, ch = bx & 3;
    const u16* kbase = kbt + ((size_t)(b * 4 + h) * 1024 + ch * 256) * 64;
    const u16* vbase = vbt + ((size_t)(b * 4 + h) * 1024 + ch * 256) * 64;
    const int d = t >> 2, v0 = (t & 3) * 16;
    float4 acc[4];
#pragma unroll
    for (int j = 0; j < 4; ++j) acc[j] = make_float4(0.f, 0.f, 0.f, 0.f);
    float ks = 0.f;
    for (int st = 0; st < 4; ++st) {
        __syncthreads();
        {
            int s = t >> 2, d0 = (t & 3) * 16;
            const u16* krow = kbase + (size_t)(st * 64 + s) * 64;
            const u16* vrow = vbase + (size_t)(st * 64 + s) * 64;
#pragma unroll
            for (int oo = 0; oo < 2; ++oo) {
                int4 k8 = *(const int4*)&krow[d0 + oo * 8];
                int4 v8 = *(const int4*)&vrow[d0 + oo * 8];
                const u16* ku = (const u16*)&k8;
                const u16* vu = (const u16*)&v8;
#pragma unroll
                for (int e = 0; e < 8; ++e) {
                    Kt[s * 68 + d0 + oo * 8 + e] = elu1(bf2f(ku[e]));
                    Vt[s * 64 + d0 + oo * 8 + e] = bf2f(vu[e]);
                }
            }
        }
        __syncthreads();
#pragma unroll 8
        for (int s = 0; s < 64; ++s) {
            float kf = Kt[s * 68 + d];
            const float4* vvp = (const float4*)(Vt + s * 64 + v0);
#pragma unroll
            for (int j = 0; j < 4; ++j) {
                float4 vv = vvp[j];
                acc[j].x += kf * vv.x; acc[j].y += kf * vv.y;
                acc[j].z += kf * vv.z; acc[j].w += kf * vv.w;
            }
        }
        if (t < 64) {
#pragma unroll 8
            for (int s = 0; s < 64; ++s) ks += Kt[s * 68 + t];
        }
    }
    float* op = KVp + ((size_t)((ch * 32 + b * 4 + h) * 64 + d)) * 64 + v0;
#pragma unroll
    for (int j = 0; j < 4; ++j) ((float4*)op)[j] = acc[j];
    if (t < 64) Ksump[(size_t)(ch * 32 + b * 4 + h) * 64 + t] = ks;
}

// ===========================================================================
// qk_sm (R18: 38.9KB LDS union, inv via LDS) || msg (R18: 2-head passes,
// 32 blocks). Math identical to validated R17.
// ===========================================================================
__global__ __launch_bounds__(512) void qk_sm_msg_kernel(
    const u16* __restrict__ qbt, const u16* __restrict__ kbt,
    float* __restrict__ vis,
    const float* __restrict__ KVp, const float* __restrict__ Ksump,
    float* __restrict__ msg)
{
    __shared__ float4 smem4[2432];      // 38,912 B union
    const int t = threadIdx.x;
    if (blockIdx.x < 1024) {
        u16* kf = (u16*)smem4;                          // 32 KB
        u16* qf = (u16*)smem4 + 32 * 512;               // 4 KB
        float* redM = (float*)((char*)smem4 + 36864);   // 1 KB
        float* redS = redM + 256;                       // 1 KB -> 38912
        const int bx = blockIdx.x;
        const int b = bx >> 7, h = (bx >> 5) & 3, l0 = (bx & 31) * 32;
        const u16* qtp = qbt + ((size_t)(b * 4 + h)) * 1024 * 64;
        const u16* ktp = kbt + ((size_t)(b * 4 + h)) * 1024 * 64;

        if (t < 256) {
            int r = t & 31, dblk = t >> 5;
            int4 pk = *(const int4*)&qtp[(size_t)(l0 + r) * 64 + dblk * 8];
            *(int4*)&qf[(((r >> 4) * 2 + (dblk >> 2)) * 64 + (dblk & 3) * 16 + (r & 15)) * 8] = pk;
        }
        __syncthreads();

        const int w = t >> 6, l = t & 63, ln = l & 15, lg = l >> 4;
        bf16x8 a[2][2];
#pragma unroll
        for (int fr = 0; fr < 2; ++fr)
#pragma unroll
            for (int ks = 0; ks < 2; ++ks)
                a[fr][ks] = *(const bf16x8*)&qf[((fr * 2 + ks) * 64 + l) * 8];

        f32x4 acc[2][4][2];
#pragma unroll
        for (int fr = 0; fr < 2; ++fr)
#pragma unroll
            for (int cc = 0; cc < 4; ++cc)
#pragma unroll
                for (int f = 0; f < 2; ++f) acc[fr][cc][f] = (f32x4){0.f, 0.f, 0.f, 0.f};

#pragma unroll
        for (int cc = 0; cc < 4; ++cc) {
            __syncthreads();
#pragma unroll
            for (int it = 0; it < 4; ++it) {
                int unit = it * 512 + t;
                int sl = unit & 255, dblk = unit >> 8;
                int4 pk = *(const int4*)&ktp[(size_t)(cc * 256 + sl) * 64 + dblk * 8];
                *(int4*)&kf[(((sl >> 4) * 2 + (dblk >> 2)) * 64 + (dblk & 3) * 16 + (sl & 15)) * 8] = pk;
            }
            __syncthreads();
#pragma unroll
            for (int f = 0; f < 2; ++f) {
                int fg = (w * 2 + f) * 2;
                bf16x8 b0 = *(const bf16x8*)&kf[((fg + 0) * 64 + l) * 8];
                bf16x8 b1 = *(const bf16x8*)&kf[((fg + 1) * 64 + l) * 8];
#pragma unroll
                for (int fr = 0; fr < 2; ++fr) {
                    acc[fr][cc][f] = __builtin_amdgcn_mfma_f32_16x16x32_bf16(a[fr][0], b0, acc[fr][cc][f], 0, 0, 0);
                    acc[fr][cc][f] = __builtin_amdgcn_mfma_f32_16x16x32_bf16(a[fr][1], b1, acc[fr][cc][f], 0, 0, 0);
                }
            }
        }

#pragma unroll
        for (int fr = 0; fr < 2; ++fr)
#pragma unroll
            for (int cc = 0; cc < 4; ++cc)
#pragma unroll
                for (int f = 0; f < 2; ++f)
#pragma unroll
                    for (int e = 0; e < 4; ++e) acc[fr][cc][f][e] *= 0.125f;

        float rmax[2][4];
#pragma unroll
        for (int fr = 0; fr < 2; ++fr)
#pragma unroll
            for (int reg = 0; reg < 4; ++reg) {
                float m = -1e30f;
#pragma unroll
                for (int cc = 0; cc < 4; ++cc)
#pragma unroll
                    for (int f = 0; f < 2; ++f) m = fmaxf(m, acc[fr][cc][f][reg]);
#pragma unroll
                for (int off = 1; off < 16; off <<= 1) m = fmaxf(m, __shfl_xor(m, off));
                if (ln == 0) redM[(fr * 16 + lg * 4 + reg) * 8 + w] = m;
                rmax[fr][reg] = m;
            }
        __syncthreads();
#pragma unroll
        for (int fr = 0; fr < 2; ++fr)
#pragma unroll
            for (int reg = 0; reg < 4; ++reg) {
                int r = fr * 16 + lg * 4 + reg;
                float m = redM[r * 8];
#pragma unroll
                for (int ww = 1; ww < 8; ++ww) m = fmaxf(m, redM[r * 8 + ww]);
                rmax[fr][reg] = m;
            }
#pragma unroll
        for (int fr = 0; fr < 2; ++fr)
#pragma unroll
            for (int reg = 0; reg < 4; ++reg) {
                float s = 0.f;
                float m = rmax[fr][reg];
#pragma unroll
                for (int cc = 0; cc < 4; ++cc)
#pragma unroll
                    for (int f = 0; f < 2; ++f) {
                        float e = __expf(acc[fr][cc][f][reg] - m);
                        acc[fr][cc][f][reg] = e;
                        s += e;
                    }
#pragma unroll
                for (int off = 1; off < 16; off <<= 1) s += __shfl_xor(s, off);
                if (ln == 0) redS[(fr * 16 + lg * 4 + reg) * 8 + w] = s;
            }
        __syncthreads();
        // per-row inverse into redM (frees 8 VGPRs vs register invv)
        if (t < 32) {
            float s = 0.f;
#pragma unroll
            for (int ww = 0; ww < 8; ++ww) s += redS[t * 8 + ww];
            redM[t] = 1.f / s;
        }
        __syncthreads();
        float* outT = (float*)smem4;    // [32][260] f32, aliases kf/qf (dead)
        float* visp = vis + (((size_t)(b * 4 + h)) << 20);
#pragma unroll
        for (int cc = 0; cc < 4; ++cc) {
            __syncthreads();
#pragma unroll
            for (int fr = 0; fr < 2; ++fr)
#pragma unroll
                for (int reg = 0; reg < 4; ++reg) {
                    int r = fr * 16 + lg * 4 + reg;
                    float inv = redM[r];
#pragma unroll
                    for (int f = 0; f < 2; ++f)
                        outT[r * 260 + w * 32 + f * 16 + ln] = acc[fr][cc][f][reg] * inv;
                }
            __syncthreads();
#pragma unroll
            for (int u = 0; u < 4; ++u) {
                int unit = u * 512 + t;
                int r = unit >> 6, c4 = unit & 63;
                f32x4 v = *(const f32x4*)&outT[r * 260 + c4 * 4];
                __builtin_nontemporal_store(v,
                    (f32x4*)&visp[(size_t)(l0 + r) * 1024 + cc * 256 + c4 * 4]);
            }
        }
        return;
    }
    // ---- msg path (32 blocks, 512 threads, 2 head-pair passes) ----
    float* kvl = (float*)smem4;             // [2][4112] = 32,896 B
    float* ksl = (float*)smem4 + 2 * 4112;  // [2][65]   -> 33,416 B total
    const int bx2 = blockIdx.x - 1024;      // 0..31
    const int b = bx2 >> 2, l0 = (bx2 & 3) * 256;
    const int hoff = t & 1, lrow = l0 + (t >> 1);
    for (int p = 0; p < 2; ++p) {
        __syncthreads();
        // stage KV for heads 2p, 2p+1 (sum 4 chunks), 2048 f4 units
#pragma unroll
        for (int m = 0; m < 4; ++m) {
            int unit = t + (m << 9);
            int hh = unit >> 10, rem = unit & 1023;
            int dd = rem >> 4, v4 = rem & 15;
            float4 s = make_float4(0.f, 0.f, 0.f, 0.f);
#pragma unroll
            for (int ch = 0; ch < 4; ++ch) {
                float4 u = *(const float4*)&KVp[((size_t)(ch * 32 + b * 4 + 2 * p + hh)) * 4096 + (size_t)rem * 4];
                s.x += u.x; s.y += u.y; s.z += u.z; s.w += u.w;
            }
            *(float4*)&kvl[hh * 4112 + dd * 64 + v4 * 4] = s;
        }
        if (t < 128) {
            int hh = t >> 6, dd = t & 63;
            float s = 0.f;
#pragma unroll
            for (int ch = 0; ch < 4; ++ch)
                s += Ksump[(size_t)(ch * 32 + b * 4 + 2 * p + hh) * 64 + dd];
            ksl[hh * 65 + dd] = s;
        }
        __syncthreads();
        const int h = 2 * p + hoff;
        const u16* qrow = qbt + ((size_t)(b * 4 + h) * 1024 + lrow) * 64;
        float qf[64];
#pragma unroll
        for (int j8 = 0; j8 < 8; ++j8) {
            int4 pk = *(const int4*)&qrow[j8 * 8];
            const u16* pku = (const u16*)&pk;
#pragma unroll
            for (int e = 0; e < 8; ++e) qf[j8 * 8 + e] = elu1(bf2f(pku[e]));
        }
        float zd = 1e-6f;
#pragma unroll
        for (int dd = 0; dd < 64; ++dd) zd += qf[dd] * ksl[hoff * 65 + dd];
        const float Z = 1.f / zd;
        float* op = msg + ((size_t)(b * 1024 + lrow)) * 256 + h * 64;
        for (int c0 = 0; c0 < 64; c0 += 16) {
            float4 a[4];
#pragma unroll
            for (int j = 0; j < 4; ++j) a[j] = make_float4(0.f, 0.f, 0.f, 0.f);
#pragma unroll
            for (int dd = 0; dd < 64; ++dd) {
                float qv = qf[dd];
                const float4* kp = (const float4*)(kvl + hoff * 4112 + dd * 64 + c0);
#pragma unroll
                for (int j = 0; j < 4; ++j) {
                    float4 kk = kp[j];
                    a[j].x += qv * kk.x; a[j].y += qv * kk.y;
                    a[j].z += qv * kk.z; a[j].w += qv * kk.w;
                }
            }
#pragma unroll
            for (int j = 0; j < 4; ++j) {
                a[j].x *= Z; a[j].y *= Z; a[j].z *= Z; a[j].w *= Z;
                ((float4*)(op + c0))[j] = a[j];
            }
        }
    }
}

// ===========================================================================
// Fused merge(Wm,LN1) + FF(W1,relu,W2,LN2) + residual (validated R12).
// ===========================================================================
__global__ __launch_bounds__(256) void ff_fused_kernel(
    const float* __restrict__ x, const float* __restrict__ msg,
    const u16* __restrict__ wmp,
    const u16* __restrict__ w1p, const u16* __restrict__ w2p,
    const float* __restrict__ g1, const float* __restrict__ b1,
    const float* __restrict__ g2, const float* __restrict__ b2,
    float* __restrict__ out)
{
    __shared__ u16 tile[16 * 520];
    __shared__ u16 mtile[16 * 264];
    __shared__ float redS[16 * 4];
    __shared__ float redQ[16 * 4];
    float* tf = (float*)tile;
    const int t = threadIdx.x;
    const int base = blockIdx.x * 16;   // 512 blocks
    const int b = base >> 10, l0 = base & 1023;
    const int w = t >> 6, l = t & 63, ln = l & 15, lg = l >> 4;

    {
        int rr = t & 15, cg = t >> 4;
        for (int cci = 0; cci < 16; ++cci) {
            int c = cci * 16 + cg;
            tile[rr * 520 + c] = f2bf(x[((size_t)b * 256 + c) * 1024 + l0 + rr]);
        }
        int r = t >> 4, cb = (t & 15) * 16;
#pragma unroll
        for (int i = 0; i < 4; ++i) {
            float4 v = *(const float4*)&msg[((size_t)(base + r)) * 256 + cb + i * 4];
            u32 p0 = (u32)f2bf(v.x) | ((u32)f2bf(v.y) << 16);
            u32 p1 = (u32)f2bf(v.z) | ((u32)f2bf(v.w) << 16);
            *(u32*)&mtile[r * 264 + cb + i * 4] = p0;
            *(u32*)&mtile[r * 264 + cb + i * 4 + 2] = p1;
        }
    }
    __syncthreads();

    f32x4 accm[4];
#pragma unroll
    for (int fc = 0; fc < 4; ++fc) accm[fc] = (f32x4){0.f, 0.f, 0.f, 0.f};
    for (int ks = 0; ks < 8; ++ks) {
        bf16x8 a0 = *(const bf16x8*)&mtile[ln * 264 + ks * 32 + lg * 8];
#pragma unroll
        for (int fc = 0; fc < 4; ++fc) {
            bf16x8 bb = *(const bf16x8*)&wmp[((size_t)(ks * 16 + w * 4 + fc) * 64 + l) * 8];
            accm[fc] = __builtin_amdgcn_mfma_f32_16x16x32_bf16(a0, bb, accm[fc], 0, 0, 0);
        }
    }
#pragma unroll
    for (int reg = 0; reg < 4; ++reg) {
        float s = 0.f, qsum = 0.f;
#pragma unroll
        for (int fc = 0; fc < 4; ++fc) {
            float v = accm[fc][reg];
            s += v; qsum += v * v;
        }
#pragma unroll
        for (int off = 1; off < 16; off <<= 1) {
            s += __shfl_xor(s, off);
            qsum += __shfl_xor(qsum, off);
        }
        if (ln == 0) {
            int r = lg * 4 + reg;
            redS[r * 4 + w] = s;
            redQ[r * 4 + w] = qsum;
        }
    }
    __syncthreads();
#pragma unroll
    for (int fc = 0; fc < 4; ++fc) {
        int c = w * 64 + fc * 16 + ln;
        float gg = g1[c], bb = b1[c];
#pragma unroll
        for (int reg = 0; reg < 4; ++reg) {
            int r = lg * 4 + reg;
            float s = redS[r * 4] + redS[r * 4 + 1] + redS[r * 4 + 2] + redS[r * 4 + 3];
            float qs = redQ[r * 4] + redQ[r * 4 + 1] + redQ[r * 4 + 2] + redQ[r * 4 + 3];
            float mean = s * (1.f / 256.f);
            float rstd = rsqrtf(qs * (1.f / 256.f) - mean * mean + 1e-5f);
            tile[r * 520 + 256 + c] = f2bf((accm[fc][reg] - mean) * rstd * gg + bb);
        }
    }
    __syncthreads();

    f32x4 acc1[8];
#pragma unroll
    for (int fc = 0; fc < 8; ++fc) acc1[fc] = (f32x4){0.f, 0.f, 0.f, 0.f};
    for (int ks = 0; ks < 16; ++ks) {
        bf16x8 a0 = *(const bf16x8*)&tile[ln * 520 + ks * 32 + lg * 8];
#pragma unroll
        for (int fc = 0; fc < 8; ++fc) {
            bf16x8 bb = *(const bf16x8*)&w1p[((size_t)(ks * 32 + w * 8 + fc) * 64 + l) * 8];
            acc1[fc] = __builtin_amdgcn_mfma_f32_16x16x32_bf16(a0, bb, acc1[fc], 0, 0, 0);
        }
    }
    __syncthreads();
#pragma unroll
    for (int fc = 0; fc < 8; ++fc)
#pragma unroll
        for (int reg = 0; reg < 4; ++reg) {
            int r = lg * 4 + reg;
            int c = w * 128 + fc * 16 + ln;
            tile[r * 520 + c] = f2bf(fmaxf(acc1[fc][reg], 0.f));
        }
    __syncthreads();

    f32x4 acc2[4];
#pragma unroll
    for (int fc = 0; fc < 4; ++fc) acc2[fc] = (f32x4){0.f, 0.f, 0.f, 0.f};
    for (int ks = 0; ks < 16; ++ks) {
        bf16x8 a0 = *(const bf16x8*)&tile[ln * 520 + ks * 32 + lg * 8];
#pragma unroll
        for (int fc = 0; fc < 4; ++fc) {
            bf16x8 bb = *(const bf16x8*)&w2p[((size_t)(ks * 16 + w * 4 + fc) * 64 + l) * 8];
            acc2[fc] = __builtin_amdgcn_mfma_f32_16x16x32_bf16(a0, bb, acc2[fc], 0, 0, 0);
        }
    }
#pragma unroll
    for (int reg = 0; reg < 4; ++reg) {
        float s = 0.f, qsum = 0.f;
#pragma unroll
        for (int fc = 0; fc < 4; ++fc) {
            float v = acc2[fc][reg];
            s += v; qsum += v * v;
        }
#pragma unroll
        for (int off = 1; off < 16; off <<= 1) {
            s += __shfl_xor(s, off);
            qsum += __shfl_xor(qsum, off);
        }
        if (ln == 0) {
            int r = lg * 4 + reg;
            redS[r * 4 + w] = s;
            redQ[r * 4 + w] = qsum;
        }
    }
    __syncthreads();
    float mean[4], rstd[4];
#pragma unroll
    for (int reg = 0; reg < 4; ++reg) {
        int r = lg * 4 + reg;
        float s = redS[r * 4] + redS[r * 4 + 1] + redS[r * 4 + 2] + redS[r * 4 + 3];
        float qs = redQ[r * 4] + redQ[r * 4 + 1] + redQ[r * 4 + 2] + redQ[r * 4 + 3];
        float m = s * (1.f / 256.f);
        mean[reg] = m;
        rstd[reg] = rsqrtf(qs * (1.f / 256.f) - m * m + 1e-5f);
    }
    __syncthreads();
#pragma unroll
    for (int fc = 0; fc < 4; ++fc) {
        int c = w * 64 + fc * 16 + ln;
        float gg = g2[c], bb = b2[c];
#pragma unroll
        for (int reg = 0; reg < 4; ++reg) {
            int r = lg * 4 + reg;
            tf[r * 260 + c] = (acc2[fc][reg] - mean[reg]) * rstd[reg] * gg + bb;
        }
    }
    __syncthreads();
    {
        const float* xp = x + ((size_t)b * 256 + t) * 1024 + l0;
        float* op = out + ((size_t)b * 256 + t) * 1024 + l0;
#pragma unroll
        for (int i = 0; i < 4; ++i) {
            float4 xv = *(const float4*)(xp + i * 4);
            float4 o;
            o.x = xv.x + tf[(i * 4 + 0) * 260 + t];
            o.y = xv.y + tf[(i * 4 + 1) * 260 + t];
            o.z = xv.z + tf[(i * 4 + 2) * 260 + t];
            o.w = xv.w + tf[(i * 4 + 3) * 260 + t];
            *(float4*)(op + i * 4) = o;
        }
    }
}

// ---------------------------------------------------------------------------
extern "C" void kernel_launch(void* const* d_in, const int* in_sizes, int n_in,
                              void* d_out, int out_size, void* d_ws, size_t ws_size,
                              hipStream_t stream)
{
    const float* x    = (const float*)d_in[0];
    const float* src  = (const float*)d_in[1];
    const float* Wq   = (const float*)d_in[2];
    const float* Wk1  = (const float*)d_in[3];
    const float* Wk3  = (const float*)d_in[4];
    const float* Wk5  = (const float*)d_in[5];
    const float* Wk7  = (const float*)d_in[6];
    const float* Wv1  = (const float*)d_in[7];
    const float* Wv3  = (const float*)d_in[8];
    const float* Wv5  = (const float*)d_in[9];
    const float* Wv7  = (const float*)d_in[10];
    const float* Wm   = (const float*)d_in[11];
    const float* g1   = (const float*)d_in[12];
    const float* b1   = (const float*)d_in[13];
    const float* g2   = (const float*)d_in[14];
    const float* b2   = (const float*)d_in[15];
    const float* W1   = (const float*)d_in[16];
    const float* W2   = (const float*)d_in[17];

    float* out = (float*)d_out;
    float* vis = out + 2097152;          // [b,h,l,s]

    // bf16 conv partials in vis region (dead until qk_sm overwrites it):
    u16* pq = (u16*)vis;                 // [4][2][8][65536]
    u16* p3 = pq + 4194304;              // [2][2][8][65536]
    u16* p5 = p3 + 2097152;              // [2][4][8][65536]
    u16* p7 = p5 + 4194304;              // [2][8][8][65536]

    // ws extent+lifetime map (float offsets; unchanged from R17):
    float* ws    = (float*)d_ws;
    u16*   qbt   = (u16*)ws;
    u16*   kbt   = (u16*)(ws + 1048576);
    u16*   vbt   = (u16*)(ws + 2097152);
    u16*   wpack = (u16*)(ws + 6291456);
    u16*   w1p   = (u16*)(ws + 6291456);
    u16*   w2p   = (u16*)(ws + 6422528);
    u16*   wmp   = (u16*)(ws + 6488064);
    u16*   xbh   = (u16*)(ws + 7962624);
    u16*   sbh   = (u16*)(ws + 9011200);
    float* msg   = ws + 10059776;
    float* KVp   = ws + 12156928;
    float* Ksump = ws + 12681216;

    prep1_kernel    <<<2656, 256, 0, stream>>>(Wq, Wk1, Wk3, Wk5, Wk7,
                                               Wv1, Wv3, Wv5, Wv7, wpack,
                                               x, src, xbh, sbh);
    conv_mfma_kernel<<<608,  512, 0, stream>>>(xbh, sbh, wpack, kbt, vbt,
                                               pq, p3, p5, p7);
    prep2_kernel    <<<2784, 256, 0, stream>>>(pq, p3, p5, p7, qbt, kbt, vbt,
                                               W1, W2, Wm, w1p, w2p, wmp);
    prep3_kernel    <<<128,  256, 0, stream>>>(kbt, vbt, KVp, Ksump);
    qk_sm_msg_kernel<<<1056, 512, 0, stream>>>(qbt, kbt, vis, KVp, Ksump, msg);
    ff_fused_kernel <<<512,  256, 0, stream>>>(x, msg, wmp, w1p, w2p,
                                               g1, b1, g2, b2, out);
}

// Round 19
// 255.337 us; speedup vs baseline: 1.0796x; 1.0796x over previous
//
#include <hip/hip_runtime.h>

#define DEV __device__ __forceinline__

typedef unsigned short u16;
typedef unsigned int u32;
typedef __bf16 bf16x8 __attribute__((ext_vector_type(8)));
typedef float f32x4 __attribute__((ext_vector_type(4)));

DEV float elu1(float x) { return x > 0.f ? x + 1.f : __expf(x); }

DEV u16 f2bf(float f) {
    union { float f; unsigned u; } v; v.f = f;
    unsigned r = v.u + 0x7fffu + ((v.u >> 16) & 1u);
    return (u16)(r >> 16);
}

DEV float bf2f(u16 h) {
    union { u32 u; float f; } v; v.u = ((u32)h) << 16; return v.f;
}

// ===========================================================================
// prep1 = conv-weight repack (validated R2)  ||  cast_src (validated R5).
// ===========================================================================
__global__ __launch_bounds__(256) void prep1_kernel(
    const float* __restrict__ Wq,
    const float* __restrict__ Wk1, const float* __restrict__ Wk3,
    const float* __restrict__ Wk5, const float* __restrict__ Wk7,
    const float* __restrict__ Wv1, const float* __restrict__ Wv3,
    const float* __restrict__ Wv5, const float* __restrict__ Wv7,
    u16* __restrict__ wpack,
    const float* __restrict__ x, const float* __restrict__ src,
    u16* __restrict__ xbh, u16* __restrict__ sbh)
{
    __shared__ float lds[32 * 129];
    const int t = threadIdx.x;
    if (blockIdx.x < 1632) {
        int gid = blockIdx.x * 256 + t;
        int frag = gid >> 6, l = gid & 63;
        const float* W; int K, ocbase = 0, rel;
        if (frag < 1152) {
            W = Wq; K = 3; int slot = frag / 288; rel = frag % 288; ocbase = slot * 64;
        } else {
            int f = frag - 1152; int side = f / 2688; f %= 2688;
            if (f < 32)        { W = side ? Wv1 : Wk1; K = 1; rel = f; }
            else if (f < 320)  { W = side ? Wv3 : Wk3; K = 3; rel = f - 32; }
            else if (f < 1120) { W = side ? Wv5 : Wk5; K = 5; rel = f - 320; }
            else               { W = side ? Wv7 : Wk7; K = 7; rel = f - 1120; }
        }
        int og = rel & 3, cc = (rel >> 2) & 7, tap = rel >> 5;
        int dy = tap / K, dx = tap % K;
        int oc = ocbase + og * 16 + (l & 15);
        int c0 = cc * 32 + (l >> 4) * 8;
        u16 pk[8];
#pragma unroll
        for (int j = 0; j < 8; ++j)
            pk[j] = f2bf(W[((size_t)(oc * 256 + c0 + j) * K + dy) * K + dx]);
        *(int4*)&wpack[(size_t)frag * 512 + l * 8] = *(const int4*)pk;
        return;
    }
    const int i = blockIdx.x - 1632;    // 1024 cast_src blocks
    const int inp = i >> 9, rem = i & 511;
    const int b = rem >> 6, cc = (rem >> 3) & 7, pxb = rem & 7;
    const float* in = (inp ? src : x) + ((size_t)b * 256 + cc * 32) * 1024 + pxb * 128;
    u16* outp = (inp ? sbh : xbh) + (size_t)b * 262144 + (size_t)cc * 32768 + pxb * 128 * 32;
#pragma unroll
    for (int u = 0; u < 4; ++u) {
        int unit = t + u * 256;
        int r = unit >> 5, px4 = unit & 31;
        float4 v = *(const float4*)(in + (size_t)r * 1024 + px4 * 4);
        lds[r * 129 + px4 * 4 + 0] = v.x;
        lds[r * 129 + px4 * 4 + 1] = v.y;
        lds[r * 129 + px4 * 4 + 2] = v.z;
        lds[r * 129 + px4 * 4 + 3] = v.w;
    }
    __syncthreads();
#pragma unroll
    for (int u = 0; u < 2; ++u) {
        int unit = t + u * 256;
        int px = unit >> 2, cg = unit & 3;
        u16 pk[8];
#pragma unroll
        for (int j = 0; j < 8; ++j) pk[j] = f2bf(lds[(cg * 8 + j) * 129 + px]);
        *(int4*)&outp[px * 32 + cg * 8] = *(const int4*)pk;
    }
}

// ===========================================================================
// MFMA implicit-GEMM conv body (R9 MFMA math + R16 bf16 epilogue, validated).
// ===========================================================================
template<int K>
DEV void conv_mfma_body(const u16* __restrict__ srcb,
                        const u16* __restrict__ wsec,
                        u16* __restrict__ dst,
                        u16* Bt, int y0, int cch0, int ncc, int t)
{
    constexpr int P = K / 2;
    const int w = t >> 6, l = t & 63;
    const int chi = l >> 4, ln = l & 15;
    const int rowbase = chi * 22 + w * 2 + 3 - P;
    const int colbase = ln + 3 - P;
    f32x4 acc[4][4];
#pragma unroll
    for (int m = 0; m < 4; ++m)
#pragma unroll
        for (int n = 0; n < 4; ++n) acc[m][n] = (f32x4){0.f, 0.f, 0.f, 0.f};

    for (int cc = 0; cc < ncc; ++cc) {
        const int ccg = cch0 + cc;
        __syncthreads();
#pragma unroll
        for (int u = 0; u < 7; ++u) {
            int unit = t + (u << 9);
            if (unit < 2816) {
                int xv = unit & 31, r = unit >> 5;
                int yy = r % 22, ch = r / 22;
                int ygl = y0 - 3 + yy;
                int4 pk;
                if ((unsigned)ygl < 32u)
                    pk = *(const int4*)&srcb[(size_t)ccg * 32768 + (ygl * 32 + xv) * 32 + ch * 8];
                else
                    pk = (int4){0, 0, 0, 0};
                *(int4*)&Bt[((ch * 22 + yy) * 40 + xv + 3) * 8] = pk;
            } else if (unit < 3520) {
                int hu = unit - 2816;
                int hx = hu & 7; int xi = hx < 3 ? hx : hx + 32;
                int r = hu >> 3; int yy = r % 22, ch = r / 22;
                int4 z = {0, 0, 0, 0};
                *(int4*)&Bt[((ch * 22 + yy) * 40 + xi) * 8] = z;
            }
        }
        __syncthreads();
#pragma unroll
        for (int dy = 0; dy < K; ++dy) {
#pragma unroll
            for (int dx = 0; dx < K; ++dx) {
                const int tap = dy * K + dx;
                const u16* wp = wsec + ((size_t)(tap * 8 + ccg) * 4) * 512 + l * 8;
                bf16x8 a0 = *(const bf16x8*)(wp);
                bf16x8 a1 = *(const bf16x8*)(wp + 512);
                bf16x8 a2 = *(const bf16x8*)(wp + 1024);
                bf16x8 a3 = *(const bf16x8*)(wp + 1536);
                bf16x8 bf[4];
#pragma unroll
                for (int n = 0; n < 4; ++n) {
                    int row = rowbase + dy + (n >> 1);
                    int col = colbase + dx + (n & 1) * 16;
                    bf[n] = *(const bf16x8*)&Bt[(row * 40 + col) * 8];
                }
#pragma unroll
                for (int n = 0; n < 4; ++n) {
                    acc[0][n] = __builtin_amdgcn_mfma_f32_16x16x32_bf16(a0, bf[n], acc[0][n], 0, 0, 0);
                    acc[1][n] = __builtin_amdgcn_mfma_f32_16x16x32_bf16(a1, bf[n], acc[1][n], 0, 0, 0);
                    acc[2][n] = __builtin_amdgcn_mfma_f32_16x16x32_bf16(a2, bf[n], acc[2][n], 0, 0, 0);
                    acc[3][n] = __builtin_amdgcn_mfma_f32_16x16x32_bf16(a3, bf[n], acc[3][n], 0, 0, 0);
                }
            }
        }
    }
#pragma unroll
    for (int m = 0; m < 4; ++m)
#pragma unroll
        for (int n = 0; n < 4; ++n) {
            int y = y0 + w * 2 + (n >> 1);
            int px = y * 32 + (n & 1) * 16 + ln;
            int ocb = m * 16 + chi * 4;
            u16 pk[4];
#pragma unroll
            for (int r = 0; r < 4; ++r) pk[r] = f2bf(acc[m][n][r]);
            *(uint2*)&dst[(size_t)px * 64 + ocb] = *(const uint2*)pk;
        }
}

// Job decode (R17 load-balanced, validated): bx = b*76 + job; job = j*2 + m.
__global__ __launch_bounds__(512) void conv_mfma_kernel(
    const u16* __restrict__ xbh, const u16* __restrict__ sbh,
    const u16* __restrict__ wpack,
    u16* __restrict__ kbt, u16* __restrict__ vbt,
    u16* __restrict__ pq, u16* __restrict__ p3,
    u16* __restrict__ p5, u16* __restrict__ p7)
{
    __shared__ u16 Bt[4 * 22 * 40 * 8];
    const int bx = blockIdx.x, t = threadIdx.x;
    const int b = bx / 76, job = bx % 76;
    const int m = job & 1, j = job >> 1;
    if (j < 8) {
        int slot = j >> 1, cp = j & 1;
        conv_mfma_body<3>(xbh + (size_t)b * 262144,
                          wpack + (size_t)(slot * 288) * 512,
                          pq + ((size_t)((slot * 2 + cp) * 8 + b)) * 65536,
                          Bt, m * 16, cp * 4, 4, t);
        return;
    }
    const int s2 = j - 8;
    const int side = s2 / 15, jj = s2 % 15;
    const u16* sp = sbh + (size_t)b * 262144;
    u16* fin = side ? vbt : kbt;
    const size_t wkb = 1152 + (size_t)side * 2688;
    if (jj == 0) {
        conv_mfma_body<1>(sp, wpack + (wkb + 0) * 512,
                          fin + ((size_t)(b * 4 + 0)) * 65536, Bt, m * 16, 0, 8, t);
    } else if (jj < 3) {
        int cp = jj - 1;
        conv_mfma_body<3>(sp, wpack + (wkb + 32) * 512,
                          p3 + ((size_t)((side * 2 + cp) * 8 + b)) * 65536,
                          Bt, m * 16, cp * 4, 4, t);
    } else if (jj < 7) {
        int cp = jj - 3;
        conv_mfma_body<5>(sp, wpack + (wkb + 320) * 512,
                          p5 + ((size_t)((side * 4 + cp) * 8 + b)) * 65536,
                          Bt, m * 16, cp * 2, 2, t);
    } else {
        int cp = jj - 7;
        conv_mfma_body<7>(sp, wpack + (wkb + 1120) * 512,
                          p7 + ((size_t)((side * 8 + cp) * 8 + b)) * 65536,
                          Bt, m * 16, cp, 1, t);
    }
}

// ===========================================================================
// prep2 = bf16-partial reduce (80 images) || FF/Wm repack (validated R17).
// ===========================================================================
__global__ __launch_bounds__(256) void prep2_kernel(
    const u16* __restrict__ pq, const u16* __restrict__ p3,
    const u16* __restrict__ p5, const u16* __restrict__ p7,
    u16* __restrict__ qbt, u16* __restrict__ kbt, u16* __restrict__ vbt,
    const float* __restrict__ W1, const float* __restrict__ W2,
    const float* __restrict__ Wm,
    u16* __restrict__ w1p, u16* __restrict__ w2p, u16* __restrict__ wmp)
{
    const int t = threadIdx.x;
    if (blockIdx.x < 2560) {
        int gid = blockIdx.x * 256 + t;     // 655360 units of 8 bf16
        int u8 = gid & 8191;
        int img = gid >> 13;                // 0..79
        const u16* srcb; u16* outb; int parts;
        if (img < 32) {
            int sub = img >> 3, b_ = img & 7;
            parts = 2;
            srcb = pq + ((size_t)(sub * 2) * 8 + b_) * 65536;
            outb = qbt + ((size_t)(b_ * 4 + sub)) * 65536;
        } else if (img < 48) {
            int i2 = img - 32; int sub = i2 >> 3, b_ = i2 & 7;
            parts = 2;
            srcb = p3 + ((size_t)(sub * 2) * 8 + b_) * 65536;
            outb = (sub ? vbt : kbt) + ((size_t)(b_ * 4 + 1)) * 65536;
        } else if (img < 64) {
            int i2 = img - 48; int sub = i2 >> 3, b_ = i2 & 7;
            parts = 4;
            srcb = p5 + ((size_t)(sub * 4) * 8 + b_) * 65536;
            outb = (sub ? vbt : kbt) + ((size_t)(b_ * 4 + 2)) * 65536;
        } else {
            int i2 = img - 64; int sub = i2 >> 3, b_ = i2 & 7;
            parts = 8;
            srcb = p7 + ((size_t)(sub * 8) * 8 + b_) * 65536;
            outb = (sub ? vbt : kbt) + ((size_t)(b_ * 4 + 3)) * 65536;
        }
        float sacc[8];
#pragma unroll
        for (int e = 0; e < 8; ++e) sacc[e] = 0.f;
        for (int p = 0; p < parts; ++p) {
            int4 u = *(const int4*)&srcb[(size_t)p * 524288 + (size_t)u8 * 8];
            const u16* uu = (const u16*)&u;
#pragma unroll
            for (int e = 0; e < 8; ++e) sacc[e] += bf2f(uu[e]);
        }
        u16 pk[8];
#pragma unroll
        for (int e = 0; e < 8; ++e) pk[e] = f2bf(sacc[e]);
        *(int4*)&outb[(size_t)u8 * 8] = *(const int4*)pk;
        return;
    }
    int gid = (blockIdx.x - 2560) * 256 + t;    // 224 blocks, 896 frags
    int f = gid >> 6, l = gid & 63;
    if (f >= 896) return;
    u16 pk[8];
    if (f < 512) {
        int ks = f >> 5, nf = f & 31;
#pragma unroll
        for (int j = 0; j < 8; ++j)
            pk[j] = f2bf(W1[(size_t)(ks * 32 + (l >> 4) * 8 + j) * 512 + nf * 16 + (l & 15)]);
        *(int4*)&w1p[(size_t)f * 512 + l * 8] = *(const int4*)pk;
    } else if (f < 768) {
        int f2 = f - 512;
        int ks = f2 >> 4, nf = f2 & 15;
#pragma unroll
        for (int j = 0; j < 8; ++j)
            pk[j] = f2bf(W2[(size_t)(ks * 32 + (l >> 4) * 8 + j) * 256 + nf * 16 + (l & 15)]);
        *(int4*)&w2p[(size_t)f2 * 512 + l * 8] = *(const int4*)pk;
    } else {
        int f3 = f - 768;
        int ks = f3 >> 4, nf = f3 & 15;
#pragma unroll
        for (int j = 0; j < 8; ++j)
            pk[j] = f2bf(Wm[(size_t)(ks * 32 + (l >> 4) * 8 + j) * 256 + nf * 16 + (l & 15)]);
        *(int4*)&wmp[(size_t)f3 * 512 + l * 8] = *(const int4*)pk;
    }
}

// ===========================================================================
// prep3 = linear-attention KV/Ksum (validated R16). 128 blocks.
// ===========================================================================
__global__ __launch_bounds__(256) void prep3_kernel(
    const u16* __restrict__ kbt, const u16* __restrict__ vbt,
    float* __restrict__ KVp, float* __restrict__ Ksump)
{
    __shared__ float4 smem4[2112];
    float* Kt = (float*)smem4;              // [64][68]
    float* Vt = (float*)(smem4 + 64 * 17);  // [64][64]
    const int t = threadIdx.x;
    const int bx = blockIdx.x;              // 128
    const int b = bx >> 4, h = (bx >> 2) & 3, ch = bx & 3;
    const u16* kbase = kbt + ((size_t)(b * 4 + h) * 1024 + ch * 256) * 64;
    const u16* vbase = vbt + ((size_t)(b * 4 + h) * 1024 + ch * 256) * 64;
    const int d = t >> 2, v0 = (t & 3) * 16;
    float4 acc[4];
#pragma unroll
    for (int j = 0; j < 4; ++j) acc[j] = make_float4(0.f, 0.f, 0.f, 0.f);
    float ks = 0.f;
    for (int st = 0; st < 4; ++st) {
        __syncthreads();
        {
            int s = t >> 2, d0 = (t & 3) * 16;
            const u16* krow = kbase + (size_t)(st * 64 + s) * 64;
            const u16* vrow = vbase + (size_t)(st * 64 + s) * 64;
#pragma unroll
            for (int oo = 0; oo < 2; ++oo) {
                int4 k8 = *(const int4*)&krow[d0 + oo * 8];
                int4 v8 = *(const int4*)&vrow[d0 + oo * 8];
                const u16* ku = (const u16*)&k8;
                const u16* vu = (const u16*)&v8;
#pragma unroll
                for (int e = 0; e < 8; ++e) {
                    Kt[s * 68 + d0 + oo * 8 + e] = elu1(bf2f(ku[e]));
                    Vt[s * 64 + d0 + oo * 8 + e] = bf2f(vu[e]);
                }
            }
        }
        __syncthreads();
#pragma unroll 8
        for (int s = 0; s < 64; ++s) {
            float kf = Kt[s * 68 + d];
            const float4* vvp = (const float4*)(Vt + s * 64 + v0);
#pragma unroll
            for (int j = 0; j < 4; ++j) {
                float4 vv = vvp[j];
                acc[j].x += kf * vv.x; acc[j].y += kf * vv.y;
                acc[j].z += kf * vv.z; acc[j].w += kf * vv.w;
            }
        }
        if (t < 64) {
#pragma unroll 8
            for (int s = 0; s < 64; ++s) ks += Kt[s * 68 + t];
        }
    }
    float* op = KVp + ((size_t)((ch * 32 + b * 4 + h) * 64 + d)) * 64 + v0;
#pragma unroll
    for (int j = 0; j < 4; ++j) ((float4*)op)[j] = acc[j];
    if (t < 64) Ksump[(size_t)(ch * 32 + b * 4 + h) * 64 + t] = ks;
}

// ===========================================================================
// qk_sm (validated R12/R15; nontemporal vis stores) || msg (validated R13).
// Byte-exact revert to R17 (best measured: 84us, VGPR 88).
// ===========================================================================
__global__ __launch_bounds__(512) void qk_sm_msg_kernel(
    const u16* __restrict__ qbt, const u16* __restrict__ kbt,
    float* __restrict__ vis,
    const float* __restrict__ KVp, const float* __restrict__ Ksump,
    float* __restrict__ msg)
{
    __shared__ float4 smem4[4178];      // 66,848 B union
    const int t = threadIdx.x;
    if (blockIdx.x < 1024) {
        u16* kf = (u16*)smem4;
        u16* qf = (u16*)smem4 + 32 * 512;
        float* redM = (float*)((char*)smem4 + 36864);
        float* redS = redM + 256;
        const int bx = blockIdx.x;
        const int b = bx >> 7, h = (bx >> 5) & 3, l0 = (bx & 31) * 32;
        const u16* qtp = qbt + ((size_t)(b * 4 + h)) * 1024 * 64;
        const u16* ktp = kbt + ((size_t)(b * 4 + h)) * 1024 * 64;

        if (t < 256) {
            int r = t & 31, dblk = t >> 5;
            int4 pk = *(const int4*)&qtp[(size_t)(l0 + r) * 64 + dblk * 8];
            *(int4*)&qf[(((r >> 4) * 2 + (dblk >> 2)) * 64 + (dblk & 3) * 16 + (r & 15)) * 8] = pk;
        }
        __syncthreads();

        const int w = t >> 6, l = t & 63, ln = l & 15, lg = l >> 4;
        bf16x8 a[2][2];
#pragma unroll
        for (int fr = 0; fr < 2; ++fr)
#pragma unroll
            for (int ks = 0; ks < 2; ++ks)
                a[fr][ks] = *(const bf16x8*)&qf[((fr * 2 + ks) * 64 + l) * 8];

        f32x4 acc[2][4][2];
#pragma unroll
        for (int fr = 0; fr < 2; ++fr)
#pragma unroll
            for (int cc = 0; cc < 4; ++cc)
#pragma unroll
                for (int f = 0; f < 2; ++f) acc[fr][cc][f] = (f32x4){0.f, 0.f, 0.f, 0.f};

#pragma unroll
        for (int cc = 0; cc < 4; ++cc) {
            __syncthreads();
#pragma unroll
            for (int it = 0; it < 4; ++it) {
                int unit = it * 512 + t;
                int sl = unit & 255, dblk = unit >> 8;
                int4 pk = *(const int4*)&ktp[(size_t)(cc * 256 + sl) * 64 + dblk * 8];
                *(int4*)&kf[(((sl >> 4) * 2 + (dblk >> 2)) * 64 + (dblk & 3) * 16 + (sl & 15)) * 8] = pk;
            }
            __syncthreads();
#pragma unroll
            for (int f = 0; f < 2; ++f) {
                int fg = (w * 2 + f) * 2;
                bf16x8 b0 = *(const bf16x8*)&kf[((fg + 0) * 64 + l) * 8];
                bf16x8 b1 = *(const bf16x8*)&kf[((fg + 1) * 64 + l) * 8];
#pragma unroll
                for (int fr = 0; fr < 2; ++fr) {
                    acc[fr][cc][f] = __builtin_amdgcn_mfma_f32_16x16x32_bf16(a[fr][0], b0, acc[fr][cc][f], 0, 0, 0);
                    acc[fr][cc][f] = __builtin_amdgcn_mfma_f32_16x16x32_bf16(a[fr][1], b1, acc[fr][cc][f], 0, 0, 0);
                }
            }
        }

#pragma unroll
        for (int fr = 0; fr < 2; ++fr)
#pragma unroll
            for (int cc = 0; cc < 4; ++cc)
#pragma unroll
                for (int f = 0; f < 2; ++f)
#pragma unroll
                    for (int e = 0; e < 4; ++e) acc[fr][cc][f][e] *= 0.125f;

        float rmax[2][4];
#pragma unroll
        for (int fr = 0; fr < 2; ++fr)
#pragma unroll
            for (int reg = 0; reg < 4; ++reg) {
                float m = -1e30f;
#pragma unroll
                for (int cc = 0; cc < 4; ++cc)
#pragma unroll
                    for (int f = 0; f < 2; ++f) m = fmaxf(m, acc[fr][cc][f][reg]);
#pragma unroll
                for (int off = 1; off < 16; off <<= 1) m = fmaxf(m, __shfl_xor(m, off));
                if (ln == 0) redM[(fr * 16 + lg * 4 + reg) * 8 + w] = m;
                rmax[fr][reg] = m;
            }
        __syncthreads();
#pragma unroll
        for (int fr = 0; fr < 2; ++fr)
#pragma unroll
            for (int reg = 0; reg < 4; ++reg) {
                int r = fr * 16 + lg * 4 + reg;
                float m = redM[r * 8];
#pragma unroll
                for (int ww = 1; ww < 8; ++ww) m = fmaxf(m, redM[r * 8 + ww]);
                rmax[fr][reg] = m;
            }
#pragma unroll
        for (int fr = 0; fr < 2; ++fr)
#pragma unroll
            for (int reg = 0; reg < 4; ++reg) {
                float s = 0.f;
                float m = rmax[fr][reg];
#pragma unroll
                for (int cc = 0; cc < 4; ++cc)
#pragma unroll
                    for (int f = 0; f < 2; ++f) {
                        float e = __expf(acc[fr][cc][f][reg] - m);
                        acc[fr][cc][f][reg] = e;
                        s += e;
                    }
#pragma unroll
                for (int off = 1; off < 16; off <<= 1) s += __shfl_xor(s, off);
                if (ln == 0) redS[(fr * 16 + lg * 4 + reg) * 8 + w] = s;
            }
        __syncthreads();
        float invv[2][4];
#pragma unroll
        for (int fr = 0; fr < 2; ++fr)
#pragma unroll
            for (int reg = 0; reg < 4; ++reg) {
                int r = fr * 16 + lg * 4 + reg;
                float s = redS[r * 8] + redS[r * 8 + 1] + redS[r * 8 + 2] + redS[r * 8 + 3]
                        + redS[r * 8 + 4] + redS[r * 8 + 5] + redS[r * 8 + 6] + redS[r * 8 + 7];
                invv[fr][reg] = 1.f / s;
            }
        float* outT = (float*)smem4;    // [32][260] f32
        float* visp = vis + (((size_t)(b * 4 + h)) << 20);
#pragma unroll
        for (int cc = 0; cc < 4; ++cc) {
            __syncthreads();
#pragma unroll
            for (int fr = 0; fr < 2; ++fr)
#pragma unroll
                for (int reg = 0; reg < 4; ++reg) {
                    int r = fr * 16 + lg * 4 + reg;
#pragma unroll
                    for (int f = 0; f < 2; ++f)
                        outT[r * 260 + w * 32 + f * 16 + ln] = acc[fr][cc][f][reg] * invv[fr][reg];
                }
            __syncthreads();
#pragma unroll
            for (int u = 0; u < 4; ++u) {
                int unit = u * 512 + t;
                int r = unit >> 6, c4 = unit & 63;
                f32x4 v = *(const f32x4*)&outT[r * 260 + c4 * 4];
                __builtin_nontemporal_store(v,
                    (f32x4*)&visp[(size_t)(l0 + r) * 1024 + cc * 256 + c4 * 4]);
            }
        }
        return;
    }
    // ---- msg path (64 blocks, 512 threads) ----
    float* kvl = (float*)smem4;             // [4][4112]
    float* ksl = (float*)smem4 + 4 * 4112;  // [4][65]
    const int bx2 = blockIdx.x - 1024;
    const int b = bx2 >> 3, l0 = (bx2 & 7) * 128;
#pragma unroll
    for (int m = 0; m < 8; ++m) {
        int unit = t + (m << 9);            // 4096 float4 units
        int hh = unit >> 10, dd = (unit >> 4) & 63, v4 = unit & 15;
        float4 s = make_float4(0.f, 0.f, 0.f, 0.f);
#pragma unroll
        for (int ch = 0; ch < 4; ++ch) {
            float4 u = *(const float4*)&KVp[((size_t)(ch * 32 + b * 4)) * 4096 + (size_t)unit * 4];
            s.x += u.x; s.y += u.y; s.z += u.z; s.w += u.w;
        }
        *(float4*)&kvl[hh * 4112 + dd * 64 + v4 * 4] = s;
    }
    if (t < 256) {
        float s = 0.f;
#pragma unroll
        for (int ch = 0; ch < 4; ++ch)
            s += Ksump[(size_t)(ch * 32 + b * 4) * 64 + t];
        ksl[(t >> 6) * 65 + (t & 63)] = s;
    }
    __syncthreads();
    const int h = t & 3, l = l0 + (t >> 2);
    const u16* qrow = qbt + ((size_t)(b * 4 + h) * 1024 + l) * 64;
    float qf[64];
#pragma unroll
    for (int j8 = 0; j8 < 8; ++j8) {
        int4 pk = *(const int4*)&qrow[j8 * 8];
        const u16* pku = (const u16*)&pk;
#pragma unroll
        for (int e = 0; e < 8; ++e) qf[j8 * 8 + e] = elu1(bf2f(pku[e]));
    }
    float zd = 1e-6f;
#pragma unroll
    for (int dd = 0; dd < 64; ++dd) zd += qf[dd] * ksl[h * 65 + dd];
    const float Z = 1.f / zd;
    float* op = msg + ((size_t)(b * 1024 + l)) * 256 + h * 64;
    for (int c0 = 0; c0 < 64; c0 += 16) {
        float4 a[4];
#pragma unroll
        for (int j = 0; j < 4; ++j) a[j] = make_float4(0.f, 0.f, 0.f, 0.f);
#pragma unroll
        for (int dd = 0; dd < 64; ++dd) {
            float qv = qf[dd];
            const float4* kp = (const float4*)(kvl + h * 4112 + dd * 64 + c0);
#pragma unroll
            for (int j = 0; j < 4; ++j) {
                float4 kk = kp[j];
                a[j].x += qv * kk.x; a[j].y += qv * kk.y;
                a[j].z += qv * kk.z; a[j].w += qv * kk.w;
            }
        }
#pragma unroll
        for (int j = 0; j < 4; ++j) {
            a[j].x *= Z; a[j].y *= Z; a[j].z *= Z; a[j].w *= Z;
            ((float4*)(op + c0))[j] = a[j];
        }
    }
}

// ===========================================================================
// Fused merge(Wm,LN1) + FF(W1,relu,W2,LN2) + residual (validated R12).
// ===========================================================================
__global__ __launch_bounds__(256) void ff_fused_kernel(
    const float* __restrict__ x, const float* __restrict__ msg,
    const u16* __restrict__ wmp,
    const u16* __restrict__ w1p, const u16* __restrict__ w2p,
    const float* __restrict__ g1, const float* __restrict__ b1,
    const float* __restrict__ g2, const float* __restrict__ b2,
    float* __restrict__ out)
{
    __shared__ u16 tile[16 * 520];
    __shared__ u16 mtile[16 * 264];
    __shared__ float redS[16 * 4];
    __shared__ float redQ[16 * 4];
    float* tf = (float*)tile;
    const int t = threadIdx.x;
    const int base = blockIdx.x * 16;   // 512 blocks
    const int b = base >> 10, l0 = base & 1023;
    const int w = t >> 6, l = t & 63, ln = l & 15, lg = l >> 4;

    {
        int rr = t & 15, cg = t >> 4;
        for (int cci = 0; cci < 16; ++cci) {
            int c = cci * 16 + cg;
            tile[rr * 520 + c] = f2bf(x[((size_t)b * 256 + c) * 1024 + l0 + rr]);
        }
        int r = t >> 4, cb = (t & 15) * 16;
#pragma unroll
        for (int i = 0; i < 4; ++i) {
            float4 v = *(const float4*)&msg[((size_t)(base + r)) * 256 + cb + i * 4];
            u32 p0 = (u32)f2bf(v.x) | ((u32)f2bf(v.y) << 16);
            u32 p1 = (u32)f2bf(v.z) | ((u32)f2bf(v.w) << 16);
            *(u32*)&mtile[r * 264 + cb + i * 4] = p0;
            *(u32*)&mtile[r * 264 + cb + i * 4 + 2] = p1;
        }
    }
    __syncthreads();

    f32x4 accm[4];
#pragma unroll
    for (int fc = 0; fc < 4; ++fc) accm[fc] = (f32x4){0.f, 0.f, 0.f, 0.f};
    for (int ks = 0; ks < 8; ++ks) {
        bf16x8 a0 = *(const bf16x8*)&mtile[ln * 264 + ks * 32 + lg * 8];
#pragma unroll
        for (int fc = 0; fc < 4; ++fc) {
            bf16x8 bb = *(const bf16x8*)&wmp[((size_t)(ks * 16 + w * 4 + fc) * 64 + l) * 8];
            accm[fc] = __builtin_amdgcn_mfma_f32_16x16x32_bf16(a0, bb, accm[fc], 0, 0, 0);
        }
    }
#pragma unroll
    for (int reg = 0; reg < 4; ++reg) {
        float s = 0.f, qsum = 0.f;
#pragma unroll
        for (int fc = 0; fc < 4; ++fc) {
            float v = accm[fc][reg];
            s += v; qsum += v * v;
        }
#pragma unroll
        for (int off = 1; off < 16; off <<= 1) {
            s += __shfl_xor(s, off);
            qsum += __shfl_xor(qsum, off);
        }
        if (ln == 0) {
            int r = lg * 4 + reg;
            redS[r * 4 + w] = s;
            redQ[r * 4 + w] = qsum;
        }
    }
    __syncthreads();
#pragma unroll
    for (int fc = 0; fc < 4; ++fc) {
        int c = w * 64 + fc * 16 + ln;
        float gg = g1[c], bb = b1[c];
#pragma unroll
        for (int reg = 0; reg < 4; ++reg) {
            int r = lg * 4 + reg;
            float s = redS[r * 4] + redS[r * 4 + 1] + redS[r * 4 + 2] + redS[r * 4 + 3];
            float qs = redQ[r * 4] + redQ[r * 4 + 1] + redQ[r * 4 + 2] + redQ[r * 4 + 3];
            float mean = s * (1.f / 256.f);
            float rstd = rsqrtf(qs * (1.f / 256.f) - mean * mean + 1e-5f);
            tile[r * 520 + 256 + c] = f2bf((accm[fc][reg] - mean) * rstd * gg + bb);
        }
    }
    __syncthreads();

    f32x4 acc1[8];
#pragma unroll
    for (int fc = 0; fc < 8; ++fc) acc1[fc] = (f32x4){0.f, 0.f, 0.f, 0.f};
    for (int ks = 0; ks < 16; ++ks) {
        bf16x8 a0 = *(const bf16x8*)&tile[ln * 520 + ks * 32 + lg * 8];
#pragma unroll
        for (int fc = 0; fc < 8; ++fc) {
            bf16x8 bb = *(const bf16x8*)&w1p[((size_t)(ks * 32 + w * 8 + fc) * 64 + l) * 8];
            acc1[fc] = __builtin_amdgcn_mfma_f32_16x16x32_bf16(a0, bb, acc1[fc], 0, 0, 0);
        }
    }
    __syncthreads();
#pragma unroll
    for (int fc = 0; fc < 8; ++fc)
#pragma unroll
        for (int reg = 0; reg < 4; ++reg) {
            int r = lg * 4 + reg;
            int c = w * 128 + fc * 16 + ln;
            tile[r * 520 + c] = f2bf(fmaxf(acc1[fc][reg], 0.f));
        }
    __syncthreads();

    f32x4 acc2[4];
#pragma unroll
    for (int fc = 0; fc < 4; ++fc) acc2[fc] = (f32x4){0.f, 0.f, 0.f, 0.f};
    for (int ks = 0; ks < 16; ++ks) {
        bf16x8 a0 = *(const bf16x8*)&tile[ln * 520 + ks * 32 + lg * 8];
#pragma unroll
        for (int fc = 0; fc < 4; ++fc) {
            bf16x8 bb = *(const bf16x8*)&w2p[((size_t)(ks * 16 + w * 4 + fc) * 64 + l) * 8];
            acc2[fc] = __builtin_amdgcn_mfma_f32_16x16x32_bf16(a0, bb, acc2[fc], 0, 0, 0);
        }
    }
#pragma unroll
    for (int reg = 0; reg < 4; ++reg) {
        float s = 0.f, qsum = 0.f;
#pragma unroll
        for (int fc = 0; fc < 4; ++fc) {
            float v = acc2[fc][reg];
            s += v; qsum += v * v;
        }
#pragma unroll
        for (int off = 1; off < 16; off <<= 1) {
            s += __shfl_xor(s, off);
            qsum += __shfl_xor(qsum, off);
        }
        if (ln == 0) {
            int r = lg * 4 + reg;
            redS[r * 4 + w] = s;
            redQ[r * 4 + w] = qsum;
        }
    }
    __syncthreads();
    float mean[4], rstd[4];
#pragma unroll
    for (int reg = 0; reg < 4; ++reg) {
        int r = lg * 4 + reg;
        float s = redS[r * 4] + redS[r * 4 + 1] + redS[r * 4 + 2] + redS[r * 4 + 3];
        float qs = redQ[r * 4] + redQ[r * 4 + 1] + redQ[r * 4 + 2] + redQ[r * 4 + 3];
        float m = s * (1.f / 256.f);
        mean[reg] = m;
        rstd[reg] = rsqrtf(qs * (1.f / 256.f) - m * m + 1e-5f);
    }
    __syncthreads();
#pragma unroll
    for (int fc = 0; fc < 4; ++fc) {
        int c = w * 64 + fc * 16 + ln;
        float gg = g2[c], bb = b2[c];
#pragma unroll
        for (int reg = 0; reg < 4; ++reg) {
            int r = lg * 4 + reg;
            tf[r * 260 + c] = (acc2[fc][reg] - mean[reg]) * rstd[reg] * gg + bb;
        }
    }
    __syncthreads();
    {
        const float* xp = x + ((size_t)b * 256 + t) * 1024 + l0;
        float* op = out + ((size_t)b * 256 + t) * 1024 + l0;
#pragma unroll
        for (int i = 0; i < 4; ++i) {
            float4 xv = *(const float4*)(xp + i * 4);
            float4 o;
            o.x = xv.x + tf[(i * 4 + 0) * 260 + t];
            o.y = xv.y + tf[(i * 4 + 1) * 260 + t];
            o.z = xv.z + tf[(i * 4 + 2) * 260 + t];
            o.w = xv.w + tf[(i * 4 + 3) * 260 + t];
            *(float4*)(op + i * 4) = o;
        }
    }
}

// ---------------------------------------------------------------------------
extern "C" void kernel_launch(void* const* d_in, const int* in_sizes, int n_in,
                              void* d_out, int out_size, void* d_ws, size_t ws_size,
                              hipStream_t stream)
{
    const float* x    = (const float*)d_in[0];
    const float* src  = (const float*)d_in[1];
    const float* Wq   = (const float*)d_in[2];
    const float* Wk1  = (const float*)d_in[3];
    const float* Wk3  = (const float*)d_in[4];
    const float* Wk5  = (const float*)d_in[5];
    const float* Wk7  = (const float*)d_in[6];
    const float* Wv1  = (const float*)d_in[7];
    const float* Wv3  = (const float*)d_in[8];
    const float* Wv5  = (const float*)d_in[9];
    const float* Wv7  = (const float*)d_in[10];
    const float* Wm   = (const float*)d_in[11];
    const float* g1   = (const float*)d_in[12];
    const float* b1   = (const float*)d_in[13];
    const float* g2   = (const float*)d_in[14];
    const float* b2   = (const float*)d_in[15];
    const float* W1   = (const float*)d_in[16];
    const float* W2   = (const float*)d_in[17];

    float* out = (float*)d_out;
    float* vis = out + 2097152;          // [b,h,l,s]

    // bf16 conv partials in vis region (dead until qk_sm overwrites it):
    u16* pq = (u16*)vis;                 // [4][2][8][65536]
    u16* p3 = pq + 4194304;              // [2][2][8][65536]
    u16* p5 = p3 + 2097152;              // [2][4][8][65536]
    u16* p7 = p5 + 4194304;              // [2][8][8][65536]

    // ws extent+lifetime map (float offsets; validated R17):
    float* ws    = (float*)d_ws;
    u16*   qbt   = (u16*)ws;
    u16*   kbt   = (u16*)(ws + 1048576);
    u16*   vbt   = (u16*)(ws + 2097152);
    u16*   wpack = (u16*)(ws + 6291456);
    u16*   w1p   = (u16*)(ws + 6291456);
    u16*   w2p   = (u16*)(ws + 6422528);
    u16*   wmp   = (u16*)(ws + 6488064);
    u16*   xbh   = (u16*)(ws + 7962624);
    u16*   sbh   = (u16*)(ws + 9011200);
    float* msg   = ws + 10059776;
    float* KVp   = ws + 12156928;
    float* Ksump = ws + 12681216;

    prep1_kernel    <<<2656, 256, 0, stream>>>(Wq, Wk1, Wk3, Wk5, Wk7,
                                               Wv1, Wv3, Wv5, Wv7, wpack,
                                               x, src, xbh, sbh);
    conv_mfma_kernel<<<608,  512, 0, stream>>>(xbh, sbh, wpack, kbt, vbt,
                                               pq, p3, p5, p7);
    prep2_kernel    <<<2784, 256, 0, stream>>>(pq, p3, p5, p7, qbt, kbt, vbt,
                                               W1, W2, Wm, w1p, w2p, wmp);
    prep3_kernel    <<<128,  256, 0, stream>>>(kbt, vbt, KVp, Ksump);
    qk_sm_msg_kernel<<<1088, 512, 0, stream>>>(qbt, kbt, vis, KVp, Ksump, msg);
    ff_fused_kernel <<<512,  256, 0, stream>>>(x, msg, wmp, w1p, w2p,
                                               g1, b1, g2, b2, out);
}